// Round 10
// baseline (892.483 us; speedup 1.0000x reference)
//
#include <hip/hip_runtime.h>
#include <hip/hip_bf16.h>

#define HWs 50176      // 224*224
#define WID 224
#define OHW 200704     // 448*448

typedef __attribute__((ext_vector_type(8))) short s16x8;
typedef __attribute__((ext_vector_type(4))) float f32x4;

static __device__ __forceinline__ unsigned short f2bf(float x) {
  unsigned u = __float_as_uint(x);
  unsigned r = (u + 0x7fffu + ((u >> 16) & 1u)) >> 16;   // RNE
  return (unsigned short)r;
}
static __device__ __forceinline__ float bf2f(unsigned short b) {
  return __uint_as_float(((unsigned)b) << 16);
}

// ---------------- K0: pack conv weights into MFMA B-fragment order, split bf16 hi/lo.
// frag_id = l*288 + t*32 + ck*8 + nt  (t=tap 0..8, ck=ic/32 step 0..3, nt=oc/16 tile 0..7)
// short8 index = (frag_id*2 + spl)*64 + lane;  B[k][n]: n = nt*16 + (lane&15),
// ic = ck*32 + (lane>>4)*8 + e.  oc>=100 or ic>=100 -> 0 (padding).
__global__ void k_wt(const float* __restrict__ w_head, const float* __restrict__ w_blk,
                     unsigned short* __restrict__ bw) {
  int gid = blockIdx.x * 256 + threadIdx.x;          // 720*256 == 184320 exact
  int frag = gid >> 7, rr = gid & 127;
  int spl = rr >> 6, lane = rr & 63;
  int l = frag / 288, q = frag - l * 288;
  int t = q / 32, q2 = q - t * 32;
  int ck = q2 >> 3, nt = q2 & 7;
  int oc = nt * 16 + (lane & 15);
  int kg = lane >> 4;
  const float* src = (l == 0) ? w_head : (w_blk + (size_t)(l - 1) * 90000);
  s16x8 outv;
  #pragma unroll
  for (int e = 0; e < 8; ++e) {
    int ic = ck * 32 + kg * 8 + e;
    float w = (oc < 100 && ic < 100) ? src[oc * 900 + ic * 9 + t] : 0.f;
    unsigned short h = f2bf(w);
    unsigned short lo = f2bf(w - bf2f(h));
    outv[e] = (short)(spl ? lo : h);
  }
  ((s16x8*)bw)[gid] = outv;
}

// ---------------- K0c: w_last [36][500] -> wlT [5][104][36], oc-pad 100..103 zeroed
__global__ void k_wlT(const float* __restrict__ wlast, float* __restrict__ wlT) {
  int i = blockIdx.x * 256 + threadIdx.x;
  if (i < 18720) {
    int l = i / 3744, rem = i - l * 3744;
    int c = rem / 36, o = rem - c * 36;
    wlT[i] = (c < 100) ? wlast[o * 500 + l * 100 + c] : 0.f;
  }
}

// ---------------- K0b: xlast = b_last (convs atomically accumulate einsum partials).
__global__ void k_binit(const float* __restrict__ blast, float* __restrict__ xlast) {
  int p = blockIdx.x * 256 + threadIdx.x;
  xlast[(size_t)blockIdx.y * HWs + p] = blast[blockIdx.y];
}

// ---------------- K1: bilinear warp + concat -> NCHW activation (round-3 version)
__global__ void k_warp(const float* __restrict__ f0, const float* __restrict__ f1,
                       const float* __restrict__ fd, const float* __restrict__ fl,
                       float* __restrict__ xin) {
  int p = blockIdx.x * 256 + threadIdx.x;
  int yq = blockIdx.y;
  int y = p / WID, x = p - y * WID;
  float fx0 = fl[p];
  float fy0 = fl[HWs + p];
  float fx1 = fl[2 * HWs + p];
  float fy1 = fl[3 * HWs + p];

  #pragma unroll
  for (int img = 0; img < 2; ++img) {
    const float* src = img ? f1 : f0;
    float fx = img ? fx1 : fx0;
    float fy = img ? fy1 : fy0;
    float px = (float)x + fx, py = (float)y + fy;
    float x0f = floorf(px), y0f = floorf(py);
    float wx = px - x0f, wy = py - y0f;
    int x0 = (int)fminf(fmaxf(x0f,       0.f), 223.f);
    int x1 = (int)fminf(fmaxf(x0f + 1.f, 0.f), 223.f);
    int y0 = (int)fminf(fmaxf(y0f,       0.f), 223.f);
    int y1 = (int)fminf(fmaxf(y0f + 1.f, 0.f), 223.f);
    float w00 = (1.f - wx) * (1.f - wy), w01 = wx * (1.f - wy);
    float w10 = (1.f - wx) * wy,         w11 = wx * wy;
    int i00 = y0 * WID + x0, i01 = y0 * WID + x1;
    int i10 = y1 * WID + x0, i11 = y1 * WID + x1;
    float* dst = xin + img * 32 * HWs;
    for (int c = yq * 8; c < yq * 8 + 8; ++c) {
      const float* pl = src + c * HWs;
      dst[c * HWs + p] = w00 * pl[i00] + w01 * pl[i01]
                       + w10 * pl[i10] + w11 * pl[i11];
    }
  }
  for (int c = yq * 8; c < yq * 8 + 8; ++c)
    xin[(64 + c) * HWs + p] = fd[c * HWs + p];
  if (yq == 0) {
    xin[96 * HWs + p] = fx0; xin[97 * HWs + p] = fy0;
    xin[98 * HWs + p] = fx1; xin[99 * HWs + p] = fy1;
  }
}

// ---------------- K2: round-3 MFMA split-bf16 3x3 conv + FUSED einsum epilogue.
// grid (7, 56) x 256: block tile = 4 rows x 32 cols x 128 oc (100 real).
// Conv phase: verbatim round-3 (bit-identical outputs, 66.5us measured).
// Epilogue: stage v into LDS act[128px][stride 108] (overlays dead patch buffers),
// barrier, then 2 threads/px x 52-oc halves -> 36-out partial -> atomicAdd xlast.
// Replaces the separate k_esum pass (saves a 100MB re-read + ~50us kernel).
__global__ __launch_bounds__(256) void k_conv(
    const float* __restrict__ in, const unsigned short* __restrict__ bw,
    const float* __restrict__ avec, const float* __restrict__ mask,
    const float* __restrict__ wl, float* __restrict__ out,
    float* __restrict__ xlast) {
  __shared__ __align__(16) unsigned char sh[65280];   // 2 x 32640 patch | act overlay
  const int tid = threadIdx.x;
  const int lane = tid & 63;
  const int wv = tid >> 6;
  const int wr = wv >> 1, wz = wv & 1;
  const int c0 = blockIdx.x * 32;
  const int r0 = blockIdx.y * 4;
  const int li = lane & 15, kg = lane >> 4;

  f32x4 acc[4][4];
  #pragma unroll
  for (int a = 0; a < 4; ++a)
    #pragma unroll
    for (int b = 0; b < 4; ++b) acc[a][b] = (f32x4){0.f, 0.f, 0.f, 0.f};

  const s16x8* bp = (const s16x8*)bw;
  s16x8 bcur[4][2], bnxt[4][2];
  #pragma unroll
  for (int nt = 0; nt < 4; ++nt)
    #pragma unroll
    for (int sp = 0; sp < 2; ++sp)
      bnxt[nt][sp] = bp[(((wz * 4 + nt) * 2 + sp) << 6) + lane];

  auto STAGE = [&](int ck, unsigned char* dst) {
    for (int j = tid; j < 816; j += 256) {           // 204 rc * 4 kgs
      int kgs = j & 3;
      int rc = j >> 2;
      int pr = rc / 34, pc = rc - pr * 34;
      int gy = r0 - 1 + pr, gx = c0 - 1 + pc;
      int gb = ck * 32 + kgs * 8;
      bool inb = ((unsigned)gy < 224u) && ((unsigned)gx < 224u);
      const float* src = in + (size_t)gb * HWs + gy * WID + gx;
      s16x8 hv, lv;
      #pragma unroll
      for (int e = 0; e < 8; ++e) {
        float v = 0.f;
        if (inb && (gb + e) < 100) v = src[(size_t)e * HWs];
        unsigned short h = f2bf(v);
        unsigned short l2 = f2bf(v - bf2f(h));
        hv[e] = (short)h; lv[e] = (short)l2;
      }
      int base = rc * 160, sw = (rc & 7) << 4;
      *(s16x8*)(dst + base + ((kgs * 16) ^ sw)) = hv;
      *(s16x8*)(dst + base + ((64 + kgs * 16) ^ sw)) = lv;
    }
  };

  STAGE(0, sh);
  __syncthreads();

  for (int ck = 0; ck < 4; ++ck) {
    unsigned char* cur = sh + (ck & 1) * 32640;
    if (ck < 3) STAGE(ck + 1, sh + ((ck + 1) & 1) * 32640);

    #pragma unroll
    for (int t = 0; t < 9; ++t) {
      #pragma unroll
      for (int nt = 0; nt < 4; ++nt) {
        bcur[nt][0] = bnxt[nt][0];
        bcur[nt][1] = bnxt[nt][1];
      }
      if (t < 8 || ck < 3) {
        int nf = (t < 8) ? (t + 1) * 32 + ck * 8 : (ck + 1) * 8;
        #pragma unroll
        for (int nt = 0; nt < 4; ++nt)
          #pragma unroll
          for (int sp = 0; sp < 2; ++sp)
            bnxt[nt][sp] = bp[(((nf + wz * 4 + nt) * 2 + sp) << 6) + lane];
      }
      const int dy = t / 3 - 1, dx = t - (t / 3) * 3 - 1;
      #pragma unroll
      for (int ms = 0; ms < 4; ++ms) {
        int pr = wr * 2 + (ms >> 1) + 1 + dy;
        int pc = (ms & 1) * 16 + li + 1 + dx;
        int rc = pr * 34 + pc;
        int base = rc * 160, sw = (rc & 7) << 4;
        s16x8 ah = *(const s16x8*)(cur + base + ((kg * 16) ^ sw));
        s16x8 al = *(const s16x8*)(cur + base + ((64 + kg * 16) ^ sw));
        #pragma unroll
        for (int nt = 0; nt < 4; ++nt) {
          acc[ms][nt] = __builtin_amdgcn_mfma_f32_16x16x32_bf16(ah, bcur[nt][0], acc[ms][nt], 0, 0, 0);
          acc[ms][nt] = __builtin_amdgcn_mfma_f32_16x16x32_bf16(al, bcur[nt][0], acc[ms][nt], 0, 0, 0);
          acc[ms][nt] = __builtin_amdgcn_mfma_f32_16x16x32_bf16(ah, bcur[nt][1], acc[ms][nt], 0, 0, 0);
        }
      }
    }
    __syncthreads();                     // also makes patch buffers dead after last ck
  }

  // ---- epilogue phase A: PReLU*mask -> global (next layer) + LDS act overlay ----
  float* act = (float*)sh;               // [128 px][stride 108] f32
  float4 mv[4];
  #pragma unroll
  for (int ms = 0; ms < 4; ++ms) {
    int row = r0 + wr * 2 + (ms >> 1);
    int colb = c0 + (ms & 1) * 16 + kg * 4;
    mv[ms] = *(const float4*)&mask[row * WID + colb];
  }
  #pragma unroll
  for (int nt = 0; nt < 4; ++nt) {
    int oc = wz * 64 + nt * 16 + li;
    if (oc < 100) {
      float a = avec[oc];
      #pragma unroll
      for (int ms = 0; ms < 4; ++ms) {
        int row = r0 + wr * 2 + (ms >> 1);
        int colb = c0 + (ms & 1) * 16 + kg * 4;
        int pxb = (wr * 2 + (ms >> 1)) * 32 + (ms & 1) * 16 + kg * 4;
        f32x4 zv = acc[ms][nt];
        float4 o;
        o.x = (zv.x >= 0.f ? zv.x : a * zv.x) * mv[ms].x;
        o.y = (zv.y >= 0.f ? zv.y : a * zv.y) * mv[ms].y;
        o.z = (zv.z >= 0.f ? zv.z : a * zv.z) * mv[ms].z;
        o.w = (zv.w >= 0.f ? zv.w : a * zv.w) * mv[ms].w;
        *(float4*)&out[(size_t)oc * HWs + row * WID + colb] = o;
        act[(pxb + 0) * 108 + oc] = o.x;
        act[(pxb + 1) * 108 + oc] = o.y;
        act[(pxb + 2) * 108 + oc] = o.z;
        act[(pxb + 3) * 108 + oc] = o.w;
      }
    } else if (oc < 104) {               // pad cols 100-103 zeroed for vector einsum
      #pragma unroll
      for (int ms = 0; ms < 4; ++ms) {
        int pxb = (wr * 2 + (ms >> 1)) * 32 + (ms & 1) * 16 + kg * 4;
        act[(pxb + 0) * 108 + oc] = 0.f;
        act[(pxb + 1) * 108 + oc] = 0.f;
        act[(pxb + 2) * 108 + oc] = 0.f;
        act[(pxb + 3) * 108 + oc] = 0.f;
      }
    }
  }
  __syncthreads();

  // ---- epilogue phase B: einsum partial. thread = (px, 52-oc half) ----
  int px = tid >> 1, h = tid & 1;
  float ac[36];
  #pragma unroll
  for (int o = 0; o < 36; ++o) ac[o] = 0.f;
  #pragma unroll
  for (int j = 0; j < 13; ++j) {
    int c = h * 52 + 4 * j;
    float4 v4 = *(const float4*)&act[px * 108 + c];
    float ve[4] = {v4.x, v4.y, v4.z, v4.w};
    #pragma unroll
    for (int e = 0; e < 4; ++e) {
      float v = ve[e];
      const float4* wp = (const float4*)(wl + (c + e) * 36);
      #pragma unroll
      for (int q = 0; q < 9; ++q) {
        float4 t = wp[q];
        ac[4*q]   = fmaf(t.x, v, ac[4*q]);
        ac[4*q+1] = fmaf(t.y, v, ac[4*q+1]);
        ac[4*q+2] = fmaf(t.z, v, ac[4*q+2]);
        ac[4*q+3] = fmaf(t.w, v, ac[4*q+3]);
      }
    }
  }
  int gp = (r0 + (px >> 5)) * WID + c0 + (px & 31);
  #pragma unroll
  for (int o = 0; o < 36; ++o)
    atomicAdd(&xlast[(size_t)o * HWs + gp], ac[o]);
}

// ---------------- K4: smn halves = conv3x3(xlast[4+h*16 .. +16], w_mask), fp64 accum.
__global__ void k_smn(const float* __restrict__ xlast, const float* __restrict__ wmask,
                      const float* __restrict__ bmask, float* __restrict__ smnh) {
  __shared__ float wm[288];
  int tid = threadIdx.x;
  int h = blockIdx.y;
  for (int j = tid; j < 288; j += 64) {
    int o = j / 144, r = j - o * 144;
    wm[j] = wmask[o * 288 + h * 144 + r];
  }
  __syncthreads();
  int p = blockIdx.x * 64 + tid;
  int y = p / WID, x = p - y * WID;
  double a0 = 0.0, a1 = 0.0;
  for (int icl = 0; icl < 16; ++icl) {
    const float* pl = xlast + (size_t)(4 + h * 16 + icl) * HWs;
    #pragma unroll
    for (int dy = -1; dy <= 1; ++dy) {
      int gy = y + dy;
      if ((unsigned)gy < 224u) {
        #pragma unroll
        for (int dx = -1; dx <= 1; ++dx) {
          int gx = x + dx;
          if ((unsigned)gx < 224u) {
            double v = (double)pl[gy * WID + gx];
            int t = (dy + 1) * 3 + (dx + 1);
            a0 += (double)wm[icl * 9 + t] * v;
            a1 += (double)wm[144 + icl * 9 + t] * v;
          }
        }
      }
    }
  }
  if (h == 0) { a0 += (double)bmask[0]; a1 += (double)bmask[1]; }
  smnh[(size_t)(h * 2 + 0) * HWs + p] = (float)a0;
  smnh[(size_t)(h * 2 + 1) * HWs + p] = (float)a1;
}

// ---------------- K5: 2x bilinear upsample + mask compare (unchanged)
__global__ void k_upsample(const float* __restrict__ xlast, const float* __restrict__ smnh,
                           const float* __restrict__ smask, float* __restrict__ out) {
  int q = blockIdx.x * 256 + threadIdx.x;
  int oy = q / 448, ox = q - oy * 448;
  int ky = oy >> 1, kx = ox >> 1;
  int r0, r1, c0, c1; float wy0, wy1, wx0, wx1;
  if (oy & 1) { r0 = ky; r1 = (ky < 223) ? ky + 1 : 223; wy0 = 0.75f; wy1 = 0.25f; }
  else        { r0 = (ky > 0) ? ky - 1 : 0; r1 = ky;     wy0 = 0.25f; wy1 = 0.75f; }
  if (ox & 1) { c0 = kx; c1 = (kx < 223) ? kx + 1 : 223; wx0 = 0.75f; wx1 = 0.25f; }
  else        { c0 = (kx > 0) ? kx - 1 : 0; c1 = kx;     wx0 = 0.25f; wx1 = 0.75f; }
  float w00 = wy0 * wx0, w01 = wy0 * wx1, w10 = wy1 * wx0, w11 = wy1 * wx1;
  int i00 = r0 * WID + c0, i01 = r0 * WID + c1, i10 = r1 * WID + c0, i11 = r1 * WID + c1;
  for (int ch = 0; ch < 36; ++ch) {
    const float* pl = xlast + (size_t)ch * HWs;
    out[(size_t)ch * OHW + q] = w00 * pl[i00] + w01 * pl[i01]
                              + w10 * pl[i10] + w11 * pl[i11];
  }
  const float* sa0 = smnh;
  const float* sa1 = smnh + HWs;
  const float* sb0 = smnh + 2 * HWs;
  const float* sb1 = smnh + 3 * HWs;
  double s0 = (double)w00 * ((double)sa0[i00] + (double)sb0[i00])
            + (double)w01 * ((double)sa0[i01] + (double)sb0[i01])
            + (double)w10 * ((double)sa0[i10] + (double)sb0[i10])
            + (double)w11 * ((double)sa0[i11] + (double)sb0[i11]);
  double s1 = (double)w00 * ((double)sa1[i00] + (double)sb1[i00])
            + (double)w01 * ((double)sa1[i01] + (double)sb1[i01])
            + (double)w10 * ((double)sa1[i10] + (double)sb1[i10])
            + (double)w11 * ((double)sa1[i11] + (double)sb1[i11]);
  float mu = smask[ky * WID + kx];
  out[36 * OHW + q] = (s0 > s1) ? mu : 0.f;
}

extern "C" void kernel_launch(void* const* d_in, const int* in_sizes, int n_in,
                              void* d_out, int out_size, void* d_ws, size_t ws_size,
                              hipStream_t stream) {
  const float* feat0   = (const float*)d_in[0];
  const float* feat1   = (const float*)d_in[1];
  const float* featd   = (const float*)d_in[2];
  const float* flow    = (const float*)d_in[3];
  const float* smask   = (const float*)d_in[4];
  const float* w_head  = (const float*)d_in[5];
  const float* a_head  = (const float*)d_in[6];
  const float* w_blk   = (const float*)d_in[7];
  const float* a_blk   = (const float*)d_in[8];
  const float* w_last  = (const float*)d_in[9];
  const float* b_last  = (const float*)d_in[10];
  const float* w_mask  = (const float*)d_in[11];
  const float* b_mask  = (const float*)d_in[12];

  // ws: 2 ping-pong NCHW activation buffers + xlast + smnh + wlT + bw (~49 MB, no aliasing)
  float* B0    = (float*)d_ws;                   // warp-out / even-layer outputs
  float* B1    = B0 + (size_t)100 * HWs;         // odd-layer outputs
  float* xlast = B1 + (size_t)100 * HWs;         // 36 planes
  float* smnh  = xlast + (size_t)36 * HWs;       // 4 planes
  float* wlT   = smnh + (size_t)4 * HWs;         // 5*104*36 = 18720 floats
  unsigned short* bw = (unsigned short*)(wlT + 18720);   // 5*294912 ushorts

  k_wt<<<dim3(720), 256, 0, stream>>>(w_head, w_blk, bw);
  k_wlT<<<dim3(74), 256, 0, stream>>>(w_last, wlT);
  k_binit<<<dim3(196, 36), 256, 0, stream>>>(b_last, xlast);
  k_warp<<<dim3(196, 4), 256, 0, stream>>>(feat0, feat1, featd, flow, B0);

  dim3 cgrid(7, 56);
  k_conv<<<cgrid, 256, 0, stream>>>(B0, bw,              a_head,      smask, wlT,            B1, xlast);
  k_conv<<<cgrid, 256, 0, stream>>>(B1, bw + 1 * 294912, a_blk,       smask, wlT + 1 * 3744, B0, xlast);
  k_conv<<<cgrid, 256, 0, stream>>>(B0, bw + 2 * 294912, a_blk + 100, smask, wlT + 2 * 3744, B1, xlast);
  k_conv<<<cgrid, 256, 0, stream>>>(B1, bw + 3 * 294912, a_blk + 200, smask, wlT + 3 * 3744, B0, xlast);
  k_conv<<<cgrid, 256, 0, stream>>>(B0, bw + 4 * 294912, a_blk + 300, smask, wlT + 4 * 3744, B1, xlast);

  k_smn<<<dim3(784, 2), 64, 0, stream>>>(xlast, w_mask, b_mask, smnh);
  k_upsample<<<784, 256, 0, stream>>>(xlast, smnh, smask, (float*)d_out);
}

// Round 11
// 450.486 us; speedup vs baseline: 1.9812x; 1.9812x over previous
//
#include <hip/hip_runtime.h>
#include <hip/hip_bf16.h>

#define HWs 50176      // 224*224
#define WID 224
#define OHW 200704     // 448*448

typedef __attribute__((ext_vector_type(8))) short s16x8;
typedef __attribute__((ext_vector_type(4))) float f32x4;

static __device__ __forceinline__ unsigned short f2bf(float x) {
  unsigned u = __float_as_uint(x);
  unsigned r = (u + 0x7fffu + ((u >> 16) & 1u)) >> 16;   // RNE
  return (unsigned short)r;
}
static __device__ __forceinline__ float bf2f(unsigned short b) {
  return __uint_as_float(((unsigned)b) << 16);
}

// ---------------- K0: pack conv weights into MFMA B-fragment order, split bf16 hi/lo.
// frag_id = l*288 + t*32 + ck*8 + nt  (t=tap 0..8, ck=ic/32 step 0..3, nt=oc/16 tile 0..7)
// short8 index = (frag_id*2 + spl)*64 + lane;  B[k][n]: n = nt*16 + (lane&15),
// ic = ck*32 + (lane>>4)*8 + e.  oc>=100 or ic>=100 -> 0 (padding).
__global__ void k_wt(const float* __restrict__ w_head, const float* __restrict__ w_blk,
                     unsigned short* __restrict__ bw) {
  int gid = blockIdx.x * 256 + threadIdx.x;          // 720*256 == 184320 exact
  int frag = gid >> 7, rr = gid & 127;
  int spl = rr >> 6, lane = rr & 63;
  int l = frag / 288, q = frag - l * 288;
  int t = q / 32, q2 = q - t * 32;
  int ck = q2 >> 3, nt = q2 & 7;
  int oc = nt * 16 + (lane & 15);
  int kg = lane >> 4;
  const float* src = (l == 0) ? w_head : (w_blk + (size_t)(l - 1) * 90000);
  s16x8 outv;
  #pragma unroll
  for (int e = 0; e < 8; ++e) {
    int ic = ck * 32 + kg * 8 + e;
    float w = (oc < 100 && ic < 100) ? src[oc * 900 + ic * 9 + t] : 0.f;
    unsigned short h = f2bf(w);
    unsigned short lo = f2bf(w - bf2f(h));
    outv[e] = (short)(spl ? lo : h);
  }
  ((s16x8*)bw)[gid] = outv;
}

// ---------------- K0c: transpose w_last [36][500] -> wlT [500][36] for k_esum
__global__ void k_wlT(const float* __restrict__ wlast, float* __restrict__ wlT) {
  int i = blockIdx.x * 256 + threadIdx.x;
  if (i < 18000) {
    int il = i / 36, o = i - il * 36;
    wlT[i] = wlast[o * 500 + il];
  }
}

// ---------------- K0b: xlast = b_last (k_esum atomically accumulates).
// NOTE: xlast aliases bw, so this must launch AFTER the last k_conv.
__global__ void k_binit(const float* __restrict__ blast, float* __restrict__ xlast) {
  int p = blockIdx.x * 256 + threadIdx.x;
  xlast[(size_t)blockIdx.y * HWs + p] = blast[blockIdx.y];
}

// ---------------- K1: bilinear warp + concat (round-3 version, NCHW)
__global__ void k_warp(const float* __restrict__ f0, const float* __restrict__ f1,
                       const float* __restrict__ fd, const float* __restrict__ fl,
                       float* __restrict__ xin) {
  int p = blockIdx.x * 256 + threadIdx.x;
  int yq = blockIdx.y;
  int y = p / WID, x = p - y * WID;
  float fx0 = fl[p];
  float fy0 = fl[HWs + p];
  float fx1 = fl[2 * HWs + p];
  float fy1 = fl[3 * HWs + p];

  #pragma unroll
  for (int img = 0; img < 2; ++img) {
    const float* src = img ? f1 : f0;
    float fx = img ? fx1 : fx0;
    float fy = img ? fy1 : fy0;
    float px = (float)x + fx, py = (float)y + fy;
    float x0f = floorf(px), y0f = floorf(py);
    float wx = px - x0f, wy = py - y0f;
    int x0 = (int)fminf(fmaxf(x0f,       0.f), 223.f);
    int x1 = (int)fminf(fmaxf(x0f + 1.f, 0.f), 223.f);
    int y0 = (int)fminf(fmaxf(y0f,       0.f), 223.f);
    int y1 = (int)fminf(fmaxf(y0f + 1.f, 0.f), 223.f);
    float w00 = (1.f - wx) * (1.f - wy), w01 = wx * (1.f - wy);
    float w10 = (1.f - wx) * wy,         w11 = wx * wy;
    int i00 = y0 * WID + x0, i01 = y0 * WID + x1;
    int i10 = y1 * WID + x0, i11 = y1 * WID + x1;
    float* dst = xin + img * 32 * HWs;
    for (int c = yq * 8; c < yq * 8 + 8; ++c) {
      const float* pl = src + c * HWs;
      dst[c * HWs + p] = w00 * pl[i00] + w01 * pl[i01]
                       + w10 * pl[i10] + w11 * pl[i11];
    }
  }
  for (int c = yq * 8; c < yq * 8 + 8; ++c)
    xin[(64 + c) * HWs + p] = fd[c * HWs + p];
  if (yq == 0) {
    xin[96 * HWs + p] = fx0; xin[97 * HWs + p] = fy0;
    xin[98 * HWs + p] = fx1; xin[99 * HWs + p] = fy1;
  }
}

// ---------------- K2: round-3 MFMA split-bf16 3x3 conv (verbatim) + T1 XCD swizzle.
// grid 392 x 256: block tile = 4 rows x 32 cols x 128 oc (100 real).
// XCD swizzle: 392 = 8 XCDs x 49; tile = (orig&7)*49 + orig>>3 gives each XCD a
// contiguous 28-row band -> halo rows + activations L2-local per XCD (bijective,
// nwg%8==0). Compute/numerics bit-identical to round 3 (66.5us measured).
__global__ __launch_bounds__(256) void k_conv(
    const float* __restrict__ in, const unsigned short* __restrict__ bw,
    const float* __restrict__ avec, const float* __restrict__ mask,
    float* __restrict__ out) {
  __shared__ __align__(16) unsigned char sh[2][6 * 34 * 160];   // 2 x 32640 B
  const int tid = threadIdx.x;
  const int lane = tid & 63;
  const int wv = tid >> 6;
  const int wr = wv >> 1, wz = wv & 1;
  int orig = blockIdx.x;
  int tile = (orig & 7) * 49 + (orig >> 3);   // XCD-contiguous band mapping
  const int c0 = (tile % 7) * 32;
  const int r0 = (tile / 7) * 4;
  const int li = lane & 15, kg = lane >> 4;

  f32x4 acc[4][4];
  #pragma unroll
  for (int a = 0; a < 4; ++a)
    #pragma unroll
    for (int b = 0; b < 4; ++b) acc[a][b] = (f32x4){0.f, 0.f, 0.f, 0.f};

  const s16x8* bp = (const s16x8*)bw;
  s16x8 bcur[4][2], bnxt[4][2];
  // prefetch (ck=0, t=0) B-fragments
  #pragma unroll
  for (int nt = 0; nt < 4; ++nt)
    #pragma unroll
    for (int sp = 0; sp < 2; ++sp)
      bnxt[nt][sp] = bp[(((wz * 4 + nt) * 2 + sp) << 6) + lane];

  // stage one 32-ic chunk: 6 rows x 34 cols, tasks = (rc, kgs): 8 ic -> 2 b128 writes
  auto STAGE = [&](int ck, unsigned char* dst) {
    for (int j = tid; j < 816; j += 256) {           // 204 rc * 4 kgs
      int kgs = j & 3;
      int rc = j >> 2;
      int pr = rc / 34, pc = rc - pr * 34;
      int gy = r0 - 1 + pr, gx = c0 - 1 + pc;
      int gb = ck * 32 + kgs * 8;
      bool inb = ((unsigned)gy < 224u) && ((unsigned)gx < 224u);
      const float* src = in + (size_t)gb * HWs + gy * WID + gx;
      s16x8 hv, lv;
      #pragma unroll
      for (int e = 0; e < 8; ++e) {
        float v = 0.f;
        if (inb && (gb + e) < 100) v = src[(size_t)e * HWs];
        unsigned short h = f2bf(v);
        unsigned short l2 = f2bf(v - bf2f(h));
        hv[e] = (short)h; lv[e] = (short)l2;
      }
      int base = rc * 160, sw = (rc & 7) << 4;
      *(s16x8*)(dst + base + ((kgs * 16) ^ sw)) = hv;
      *(s16x8*)(dst + base + ((64 + kgs * 16) ^ sw)) = lv;
    }
  };

  STAGE(0, sh[0]);
  __syncthreads();

  for (int ck = 0; ck < 4; ++ck) {
    unsigned char* cur = sh[ck & 1];
    if (ck < 3) STAGE(ck + 1, sh[(ck + 1) & 1]);     // overlapped with MFMA phase

    #pragma unroll
    for (int t = 0; t < 9; ++t) {
      #pragma unroll
      for (int nt = 0; nt < 4; ++nt) {
        bcur[nt][0] = bnxt[nt][0];
        bcur[nt][1] = bnxt[nt][1];
      }
      if (t < 8 || ck < 3) {
        int nf = (t < 8) ? (t + 1) * 32 + ck * 8 : (ck + 1) * 8;
        #pragma unroll
        for (int nt = 0; nt < 4; ++nt)
          #pragma unroll
          for (int sp = 0; sp < 2; ++sp)
            bnxt[nt][sp] = bp[(((nf + wz * 4 + nt) * 2 + sp) << 6) + lane];
      }
      const int dy = t / 3 - 1, dx = t - (t / 3) * 3 - 1;
      #pragma unroll
      for (int ms = 0; ms < 4; ++ms) {
        int pr = wr * 2 + (ms >> 1) + 1 + dy;
        int pc = (ms & 1) * 16 + li + 1 + dx;
        int rc = pr * 34 + pc;
        int base = rc * 160, sw = (rc & 7) << 4;
        s16x8 ah = *(const s16x8*)(cur + base + ((kg * 16) ^ sw));
        s16x8 al = *(const s16x8*)(cur + base + ((64 + kg * 16) ^ sw));
        #pragma unroll
        for (int nt = 0; nt < 4; ++nt) {
          acc[ms][nt] = __builtin_amdgcn_mfma_f32_16x16x32_bf16(ah, bcur[nt][0], acc[ms][nt], 0, 0, 0);
          acc[ms][nt] = __builtin_amdgcn_mfma_f32_16x16x32_bf16(al, bcur[nt][0], acc[ms][nt], 0, 0, 0);
          acc[ms][nt] = __builtin_amdgcn_mfma_f32_16x16x32_bf16(ah, bcur[nt][1], acc[ms][nt], 0, 0, 0);
        }
      }
    }
    __syncthreads();
  }

  // epilogue: PReLU * mask.  D: row(pixel-within-16) = (lane>>4)*4+reg, col(oc) = lane&15
  float4 mv[4];
  #pragma unroll
  for (int ms = 0; ms < 4; ++ms) {
    int row = r0 + wr * 2 + (ms >> 1);
    int colb = c0 + (ms & 1) * 16 + kg * 4;
    mv[ms] = *(const float4*)&mask[row * WID + colb];
  }
  #pragma unroll
  for (int nt = 0; nt < 4; ++nt) {
    int oc = wz * 64 + nt * 16 + li;
    if (oc < 100) {
      float a = avec[oc];
      #pragma unroll
      for (int ms = 0; ms < 4; ++ms) {
        int row = r0 + wr * 2 + (ms >> 1);
        int colb = c0 + (ms & 1) * 16 + kg * 4;
        f32x4 zv = acc[ms][nt];
        float4 o;
        o.x = (zv.x >= 0.f ? zv.x : a * zv.x) * mv[ms].x;
        o.y = (zv.y >= 0.f ? zv.y : a * zv.y) * mv[ms].y;
        o.z = (zv.z >= 0.f ? zv.z : a * zv.z) * mv[ms].z;
        o.w = (zv.w >= 0.f ? zv.w : a * zv.w) * mv[ms].w;
        *(float4*)&out[(size_t)oc * HWs + row * WID + colb] = o;
      }
    }
  }
}

// ---------------- K3: einsum partial, K-split by layer for occupancy (round-3).
// grid (784, 5) x 64: y = layer; lane = pixel. 3920 waves (~15/CU).
__global__ __launch_bounds__(64) void k_esum(
    const float* __restrict__ A0, const float* __restrict__ A1,
    const float* __restrict__ A2, const float* __restrict__ A3,
    const float* __restrict__ A4, const float* __restrict__ wlT,
    float* __restrict__ xlast) {
  int p = blockIdx.x * 64 + threadIdx.x;
  int l = blockIdx.y;
  const float* a = (l == 0) ? A0 : (l == 1) ? A1 : (l == 2) ? A2 : (l == 3) ? A3 : A4;
  const float* w = wlT + l * 3600;
  float acc[36];
  #pragma unroll
  for (int o = 0; o < 36; ++o) acc[o] = 0.f;
  for (int c0 = 0; c0 < 100; c0 += 10) {
    float v[10];
    #pragma unroll
    for (int q = 0; q < 10; ++q)
      v[q] = a[(size_t)(c0 + q) * HWs + p];
    #pragma unroll
    for (int q = 0; q < 10; ++q) {
      const float4* wp = (const float4*)(w + (c0 + q) * 36);
      #pragma unroll
      for (int j = 0; j < 9; ++j) {
        float4 t = wp[j];
        acc[4*j]   = fmaf(t.x, v[q], acc[4*j]);
        acc[4*j+1] = fmaf(t.y, v[q], acc[4*j+1]);
        acc[4*j+2] = fmaf(t.z, v[q], acc[4*j+2]);
        acc[4*j+3] = fmaf(t.w, v[q], acc[4*j+3]);
      }
    }
  }
  #pragma unroll
  for (int o = 0; o < 36; ++o)
    atomicAdd(&xlast[(size_t)o * HWs + p], acc[o]);
}

// ---------------- K4: smn halves = conv3x3(xlast[4+h*16 .. +16], w_mask), fp64 accum.
__global__ void k_smn(const float* __restrict__ xlast, const float* __restrict__ wmask,
                      const float* __restrict__ bmask, float* __restrict__ smnh) {
  __shared__ float wm[288];
  int tid = threadIdx.x;
  int h = blockIdx.y;
  for (int j = tid; j < 288; j += 64) {
    int o = j / 144, r = j - o * 144;
    wm[j] = wmask[o * 288 + h * 144 + r];
  }
  __syncthreads();
  int p = blockIdx.x * 64 + tid;
  int y = p / WID, x = p - y * WID;
  double a0 = 0.0, a1 = 0.0;
  for (int icl = 0; icl < 16; ++icl) {
    const float* pl = xlast + (size_t)(4 + h * 16 + icl) * HWs;
    #pragma unroll
    for (int dy = -1; dy <= 1; ++dy) {
      int gy = y + dy;
      if ((unsigned)gy < 224u) {
        #pragma unroll
        for (int dx = -1; dx <= 1; ++dx) {
          int gx = x + dx;
          if ((unsigned)gx < 224u) {
            double v = (double)pl[gy * WID + gx];
            int t = (dy + 1) * 3 + (dx + 1);
            a0 += (double)wm[icl * 9 + t] * v;
            a1 += (double)wm[144 + icl * 9 + t] * v;
          }
        }
      }
    }
  }
  if (h == 0) { a0 += (double)bmask[0]; a1 += (double)bmask[1]; }
  smnh[(size_t)(h * 2 + 0) * HWs + p] = (float)a0;
  smnh[(size_t)(h * 2 + 1) * HWs + p] = (float)a1;
}

// ---------------- K5: 2x bilinear upsample + mask compare (unchanged)
__global__ void k_upsample(const float* __restrict__ xlast, const float* __restrict__ smnh,
                           const float* __restrict__ smask, float* __restrict__ out) {
  int q = blockIdx.x * 256 + threadIdx.x;
  int oy = q / 448, ox = q - oy * 448;
  int ky = oy >> 1, kx = ox >> 1;
  int r0, r1, c0, c1; float wy0, wy1, wx0, wx1;
  if (oy & 1) { r0 = ky; r1 = (ky < 223) ? ky + 1 : 223; wy0 = 0.75f; wy1 = 0.25f; }
  else        { r0 = (ky > 0) ? ky - 1 : 0; r1 = ky;     wy0 = 0.25f; wy1 = 0.75f; }
  if (ox & 1) { c0 = kx; c1 = (kx < 223) ? kx + 1 : 223; wx0 = 0.75f; wx1 = 0.25f; }
  else        { c0 = (kx > 0) ? kx - 1 : 0; c1 = kx;     wx0 = 0.25f; wx1 = 0.75f; }
  float w00 = wy0 * wx0, w01 = wy0 * wx1, w10 = wy1 * wx0, w11 = wy1 * wx1;
  int i00 = r0 * WID + c0, i01 = r0 * WID + c1, i10 = r1 * WID + c0, i11 = r1 * WID + c1;
  for (int ch = 0; ch < 36; ++ch) {
    const float* pl = xlast + (size_t)ch * HWs;
    out[(size_t)ch * OHW + q] = w00 * pl[i00] + w01 * pl[i01]
                              + w10 * pl[i10] + w11 * pl[i11];
  }
  const float* sa0 = smnh;
  const float* sa1 = smnh + HWs;
  const float* sb0 = smnh + 2 * HWs;
  const float* sb1 = smnh + 3 * HWs;
  double s0 = (double)w00 * ((double)sa0[i00] + (double)sb0[i00])
            + (double)w01 * ((double)sa0[i01] + (double)sb0[i01])
            + (double)w10 * ((double)sa0[i10] + (double)sb0[i10])
            + (double)w11 * ((double)sa0[i11] + (double)sb0[i11]);
  double s1 = (double)w00 * ((double)sa1[i00] + (double)sb1[i00])
            + (double)w01 * ((double)sa1[i01] + (double)sb1[i01])
            + (double)w10 * ((double)sa1[i10] + (double)sb1[i10])
            + (double)w11 * ((double)sa1[i11] + (double)sb1[i11]);
  float mu = smask[ky * WID + kx];
  out[36 * OHW + q] = (s0 > s1) ? mu : 0.f;
}

extern "C" void kernel_launch(void* const* d_in, const int* in_sizes, int n_in,
                              void* d_out, int out_size, void* d_ws, size_t ws_size,
                              hipStream_t stream) {
  const float* feat0   = (const float*)d_in[0];
  const float* feat1   = (const float*)d_in[1];
  const float* featd   = (const float*)d_in[2];
  const float* flow    = (const float*)d_in[3];
  const float* smask   = (const float*)d_in[4];
  const float* w_head  = (const float*)d_in[5];
  const float* a_head  = (const float*)d_in[6];
  const float* w_blk   = (const float*)d_in[7];
  const float* a_blk   = (const float*)d_in[8];
  const float* w_last  = (const float*)d_in[9];
  const float* b_last  = (const float*)d_in[10];
  const float* w_mask  = (const float*)d_in[11];
  const float* b_mask  = (const float*)d_in[12];

  // ws: 5 activation buffers + smnh + wlT; xlast aliases bw (bw dead after last conv).
  float* B0 = (float*)d_ws;                 // warp-out, then L1 output
  float* B1 = B0 + (size_t)100 * HWs;       // L0 output
  float* B2 = B1 + (size_t)100 * HWs;       // L2 output
  float* B3 = B2 + (size_t)100 * HWs;       // L3 output
  float* B4 = B3 + (size_t)100 * HWs;       // L4 output
  float* smnh = B4 + (size_t)100 * HWs;     // 4 planes
  float* wlT  = smnh + (size_t)4 * HWs;     // 18000 floats
  float* xlast = wlT + 18000;               // 36 planes, aliases bw
  unsigned short* bw = (unsigned short*)xlast;  // 5*294912 ushorts

  k_wt<<<dim3(720), 256, 0, stream>>>(w_head, w_blk, bw);
  k_wlT<<<dim3(71), 256, 0, stream>>>(w_last, wlT);
  k_warp<<<dim3(196, 4), 256, 0, stream>>>(feat0, feat1, featd, flow, B0);

  k_conv<<<392, 256, 0, stream>>>(B0, bw,               a_head,      smask, B1);
  k_conv<<<392, 256, 0, stream>>>(B1, bw + 1 * 294912,  a_blk,       smask, B0);
  k_conv<<<392, 256, 0, stream>>>(B0, bw + 2 * 294912,  a_blk + 100, smask, B2);
  k_conv<<<392, 256, 0, stream>>>(B2, bw + 3 * 294912,  a_blk + 200, smask, B3);
  k_conv<<<392, 256, 0, stream>>>(B3, bw + 4 * 294912,  a_blk + 300, smask, B4);

  // seed xlast with b_last (must be after last conv: xlast aliases bw)
  k_binit<<<dim3(196, 36), 256, 0, stream>>>(b_last, xlast);
  // feats order: [L0, L1, L2, L3, L4] = [B1, B0, B2, B3, B4]
  k_esum<<<dim3(784, 5), 64, 0, stream>>>(B1, B0, B2, B3, B4, wlT, xlast);

  k_smn<<<dim3(784, 2), 64, 0, stream>>>(xlast, w_mask, b_mask, smnh);
  k_upsample<<<784, 256, 0, stream>>>(xlast, smnh, smask, (float*)d_out);
}